// Round 8
// baseline (106.779 us; speedup 1.0000x reference)
//
#include <hip/hip_runtime.h>
#include <hip/hip_bf16.h>

// einsum("btd,de->bte"): GEMM M=256000, K=512, N=16, f32 in/out.
// A = 524 MB compulsory HBM stream. History: R3 109 (frag-pattern loads),
// v6 105.7 (block-wide contiguous staging + syncthreads), v7 104.1 (counted
// vmcnt across barriers -> convoy coupling + reduce phase remain).
// v8: fully barrier-free. Each wave owns 4 consecutive 16-row tiles with
// FULL K (no cross-wave reduce), streams its contiguous 128 KB via
// wave-private double-buffered 8 KB chunks (global_load_lds, 1 KB/instr
// contiguous), counted vmcnt(8) keeps the next chunk in flight. Zero
// s_barrier instructions. Source pre-swizzled (involution within 512 B
// rows) so frag-layout ds_read_b128 are bank-clean (rule #21).

#define D_IN   512
#define D_OUT  16
#define NROWS  (128 * 2000)       // 256000 rows -> 16000 tiles of 16 rows
#define BLOCK  256
#define TPW    4                  // tiles per wave
#define GRID   1000               // 4000 waves x 4 tiles = 16000 tiles

typedef short  short8 __attribute__((ext_vector_type(8)));
typedef float  f32x4  __attribute__((ext_vector_type(4)));

__device__ __forceinline__ unsigned int cvt2(float lo, float hi) {
    union { __hip_bfloat162 h; unsigned int u; } c;
    c.h = __float22bfloat162_rn(make_float2(lo, hi));
    return c.u;
}

__global__ __launch_bounds__(BLOCK, 2) void ts_mm_v8(
    const float* __restrict__ A,   // [NROWS, D_IN]
    const float* __restrict__ W,   // [D_IN, D_OUT]
    float* __restrict__ O)         // [NROWS, D_OUT]
{
    // Wave-private double-buffered chunk: 16 rows x 128 k x f32 = 8 KB.
    // 4 waves x 2 x 8 KB = 64 KB -> 2 blocks/CU.
    __shared__ __align__(16) char buf[4][2][8192];

    const int lane = threadIdx.x & 63;
    const int wid  = threadIdx.x >> 6;
    const int e    = lane & 15;            // frag row (A) / out col (B)
    const int g    = lane >> 4;            // k-subgroup 0..3
    const int sw   = (e & 7) << 4;         // read-side XOR swizzle

    // ---- B fragments (registers, R2-verified build): kt = 0..15 ----
    short8 bfrag[16];
#pragma unroll
    for (int kt = 0; kt < 16; ++kt) {
        const float* wp = W + (size_t)(kt * 32 + g * 8) * D_OUT + e;
        union { unsigned int u[4]; short8 s; } c;
        c.u[0] = cvt2(wp[0 * 16], wp[1 * 16]);
        c.u[1] = cvt2(wp[2 * 16], wp[3 * 16]);
        c.u[2] = cvt2(wp[4 * 16], wp[5 * 16]);
        c.u[3] = cvt2(wp[6 * 16], wp[7 * 16]);
        bfrag[kt] = c.s;
    }

    const int    wgid  = blockIdx.x * 4 + wid;      // 0..3999
    const char*  wbase = (const char*)A + (size_t)wgid * TPW * 32768;
    char* const  lbase0 = buf[wid][0];
    char* const  lbase1 = buf[wid][1];

    // Stage chunk (t, cc) into parity buffer: 8 x global_load_lds_dwordx4.
    // LDS image: row r (512 B) holds A row r's k-window [cc*128,+128),
    // bytes pre-swizzled so byte wb holds logical wb ^ ((r&7)<<4).
    auto stage = [&](int t, int cc, char* dst) {
#pragma unroll
        for (int it = 0; it < 8; ++it) {
            const int L   = it * 1024 + lane * 16;      // lds landing byte
            const int row = L >> 9;
            const int S   = (L & 511) ^ ((row & 7) << 4);
            const char* src = wbase + (size_t)t * 32768 + row * 2048 + cc * 512 + S;
            __builtin_amdgcn_global_load_lds(
                (const __attribute__((address_space(1))) void*)src,
                (__attribute__((address_space(3))) void*)(dst + it * 1024),
                16, 0, 0);
        }
    };

    // Consume chunk cc (compile-time) from rb into acc: 8 ds_read + 4 MFMA.
    auto consume = [&](const char* rb, int cc, f32x4& acc) {
#pragma unroll
        for (int j = 0; j < 4; ++j) {
            const int ra = e * 512 + j * 128 + g * 32;
            f32x4 lo = *(const f32x4*)(rb + (ra ^ sw));
            f32x4 hi = *(const f32x4*)(rb + ((ra + 16) ^ sw));
            union { unsigned int u[4]; short8 s; } c;
            c.u[0] = cvt2(lo[0], lo[1]);
            c.u[1] = cvt2(lo[2], lo[3]);
            c.u[2] = cvt2(hi[0], hi[1]);
            c.u[3] = cvt2(hi[2], hi[3]);
            acc = __builtin_amdgcn_mfma_f32_16x16x32_bf16(c.s, bfrag[cc * 4 + j], acc, 0, 0, 0);
        }
    };

    stage(0, 0, lbase0);

#pragma unroll 1
    for (int t = 0; t < TPW; ++t) {
        f32x4 acc = {0.f, 0.f, 0.f, 0.f};

        // cc = 0: consume parity 0, prefetch (t,1) into parity 1.
        stage(t, 1, lbase1);
        asm volatile("s_waitcnt vmcnt(8)" ::: "memory");
        __builtin_amdgcn_sched_barrier(0);
        consume(lbase0, 0, acc);

        // cc = 1: consume parity 1, prefetch (t,2) into parity 0.
        stage(t, 2, lbase0);
        asm volatile("s_waitcnt vmcnt(8)" ::: "memory");
        __builtin_amdgcn_sched_barrier(0);
        consume(lbase1, 1, acc);

        // cc = 2: consume parity 0, prefetch (t,3) into parity 1.
        stage(t, 3, lbase1);
        asm volatile("s_waitcnt vmcnt(8)" ::: "memory");
        __builtin_amdgcn_sched_barrier(0);
        consume(lbase0, 2, acc);

        // cc = 3: consume parity 1, prefetch (t+1,0) into parity 0.
        if (t + 1 < TPW) {
            stage(t + 1, 0, lbase0);
            asm volatile("s_waitcnt vmcnt(8)" ::: "memory");
        } else {
            asm volatile("s_waitcnt vmcnt(0)" ::: "memory");
        }
        __builtin_amdgcn_sched_barrier(0);
        consume(lbase1, 3, acc);

        // Store: lane holds rows g*4+r (r=0..3), col e; 64 B contiguous
        // per 16-lane group per store.
        const int tile = wgid * TPW + t;
        float* op = O + (size_t)tile * 256 + (size_t)(g * 4) * D_OUT + e;
        op[0 * D_OUT] = acc[0];
        op[1 * D_OUT] = acc[1];
        op[2 * D_OUT] = acc[2];
        op[3 * D_OUT] = acc[3];
    }
}

extern "C" void kernel_launch(void* const* d_in, const int* in_sizes, int n_in,
                              void* d_out, int out_size, void* d_ws, size_t ws_size,
                              hipStream_t stream) {
    const float* A = (const float*)d_in[0];   // data    [128, 2000, 512]
    const float* W = (const float*)d_in[1];   // weights [512, 16]
    float*       O = (float*)d_out;           // out     [128, 2000, 16]

    ts_mm_v8<<<dim3(GRID), dim3(BLOCK), 0, stream>>>(A, W, O);
}